// Round 11
// baseline (60.936 us; speedup 1.0000x reference)
//
#include <hip/hip_runtime.h>

typedef unsigned int uint;

constexpr int Bc = 4, Mc = 32, Hc = 152, Wc = 272;
constexpr int HWc = Hc * Wc;              // 41344
constexpr int WTc = 593;                  // (16+2)*16 + 16 + 16*16 + 16 + 16 + 1
constexpr int MG = 4;                     // m-groups per batch
constexpr int MPB = 8;                    // m's per block
constexpr int NEG_BLOCKS = 1024;          // 4 b x 4 mg x 64 chunks
constexpr int ITERS = HWc / 64;           // 646
constexpr int POS_OFF = 1024;             // ws float idx of pos terms

using f32x4 = __attribute__((ext_vector_type(4))) float;
using bf16x8 = __attribute__((ext_vector_type(8))) short;

__device__ inline uint pkbf(float lo, float hi) {
  uint r;
  asm("v_cvt_pk_bf16_f32 %0, %1, %2" : "=v"(r) : "v"(lo), "v"(hi));
  return r;
}
// convention-immune cross-half sums (self-swap): pr[0]+pr[1] == x[l] + x[l^K]
__device__ inline float xsum16(float x) {
#if __has_builtin(__builtin_amdgcn_permlane16_swap)
  uint u = __float_as_uint(x);
  auto pr = __builtin_amdgcn_permlane16_swap(u, u, false, false);
  return __uint_as_float(pr[0]) + __uint_as_float(pr[1]);
#else
  return x + __shfl_xor(x, 16);
#endif
}
__device__ inline float xsum32(float x) {
#if __has_builtin(__builtin_amdgcn_permlane32_swap)
  uint u = __float_as_uint(x);
  auto pr = __builtin_amdgcn_permlane32_swap(u, u, false, false);
  return __uint_as_float(pr[0]) + __uint_as_float(pr[1]);
#else
  return x + __shfl_xor(x, 32);
#endif
}

union FR { uint u[4]; bf16x8 v; };

// ---- single fused kernel: per-block weight gather + frag build + pos + neg ----
__global__ __launch_bounds__(256, 4) void sch_fused(const float* __restrict__ sf_all,
                                                    const float* __restrict__ cw,
                                                    const int* __restrict__ pre_ind,
                                                    const int* __restrict__ ind,
                                                    const float* __restrict__ mask,
                                                    const float* __restrict__ target,
                                                    float* __restrict__ ws) {
  __shared__ float stage[4][600];   // 9.6 KB: fp32 weights for 4 m's
  __shared__ uint4 sA1[MPB][64];    // 8 KB
  __shared__ uint2 sA2[MPB][64];    // 4 KB
  __shared__ float sW3[MPB][20];    // w3[16], b3
  __shared__ float sCB[MPB][32];    // c1eff[16], b2[16]
  __shared__ float sh1[4][16], sh2[4][16];
  __shared__ uint  xp[4][768];      // 12 KB wave-private transpose buffer
  __shared__ float red[256];

  const int tid = threadIdx.x;
  const int lane = tid & 63;
  const int wid = tid >> 6;
  // XCD-aware: batch b pinned to XCD pair {2b,2b+1}
  const int xcd = blockIdx.x & 7;
  const int slot = blockIdx.x >> 3;               // 0..127
  const int b = xcd >> 1;
  const int mg = slot & 3;
  const int nb = ((slot >> 2) << 1) | (xcd & 1);  // 0..63
  const int bmBase = b * 32 + mg * MPB;
  const int g = lane >> 4, o = lane & 15;
  const bool posBlock = (nb == 0);

  const float* sf = sf_all + (size_t)b * 16 * HWc;

  // ======== Phase A: gather weights (L2-amortized across 64 sibling blocks),
  //          build MFMA fragments + fp32 consts; pos terms on nb==0 blocks ========
  for (int rnd = 0; rnd < 2; ++rnd) {
    const int m0 = rnd * 4;
    for (int e = tid; e < 4 * WTc; e += 256) {
      const int mj = e / WTc, j = e - mj * WTc;
      const int p = pre_ind[bmBase + m0 + mj];
      stage[mj][j] = cw[((size_t)b * WTc + j) * HWc + p];
    }
    __syncthreads();

    if (tid < 64) {
#pragma unroll
      for (int mj = 0; mj < 4; ++mj) {
        float a1f[8], a2f[8];
#pragma unroll
        for (int e = 0; e < 8; e++) {
          int k = 8 * g + e;
          a1f[e] = (k < 18) ? stage[mj][o * 18 + k] : 0.0f;       // k=16,17 coord weights
          a2f[e] = (e < 4) ? stage[mj][304 + o * 16 + 4 * g + e] : 0.0f;  // D1-native
        }
        uint4 u1; uint2 u2;
        u1.x = pkbf(a1f[0], a1f[1]); u1.y = pkbf(a1f[2], a1f[3]);
        u1.z = pkbf(a1f[4], a1f[5]); u1.w = pkbf(a1f[6], a1f[7]);
        u2.x = pkbf(a2f[0], a2f[1]); u2.y = pkbf(a2f[2], a2f[3]);
        sA1[m0 + mj][tid] = u1;
        sA2[m0 + mj][tid] = u2;
      }
    } else if (tid >= 128 && tid < 192) {
      const int mj = (tid - 128) >> 4, row = tid & 15;
      const int p = pre_ind[bmBase + m0 + mj];
      const float x0 = (float)(p % Wc);
      const float y0 = (float)p / (float)Wc;  // float division of flat index (per ref)
      sCB[m0 + mj][row] = stage[mj][288 + row] -
          (stage[mj][row * 18 + 16] * x0 + stage[mj][row * 18 + 17] * y0) * 0.0078125f;
      sCB[m0 + mj][16 + row] = stage[mj][560 + row];
    } else if (tid >= 192) {
      const int mj = (tid - 192) >> 4, k = tid & 15;
      sW3[m0 + mj][k] = stage[mj][576 + k];
      if (k == 0) sW3[m0 + mj][16] = stage[mj][592];
    }
    // pos layer 1 (exact fp32), threads 64..127 on pos blocks
    if (posBlock && tid >= 64 && tid < 128) {
      const int mj = (tid - 64) >> 4, row = tid & 15;
      const int bm = bmBase + m0 + mj;
      const int p = pre_ind[bm];
      const int pi = ind[bm];
      const float x0 = (float)(p % Wc);
      const float y0 = (float)p / (float)Wc;
      float f[18];
#pragma unroll
      for (int c = 0; c < 16; c++) f[c] = sf[(size_t)c * HWc + pi];
      const int hh = pi / Wc;
      f[16] = ((float)(pi - hh * Wc) - x0) * 0.0078125f;
      f[17] = ((float)hh - y0) * 0.0078125f;
      float a = stage[mj][288 + row];
#pragma unroll
      for (int c = 0; c < 18; c++) a = fmaf(stage[mj][row * 18 + c], f[c], a);
      sh1[mj][row] = fmaxf(a, 0.0f);
    }
    __syncthreads();
    if (posBlock && tid >= 64 && tid < 128) {
      const int mj = (tid - 64) >> 4, row = tid & 15;
      float a = stage[mj][560 + row];
#pragma unroll
      for (int c = 0; c < 16; c++) a = fmaf(stage[mj][304 + row * 16 + c], sh1[mj][c], a);
      sh2[mj][row] = fmaxf(a, 0.0f);
    }
    __syncthreads();
    if (posBlock && tid >= 64 && tid < 128 && (tid & 15) == 0) {
      const int mj = (tid - 64) >> 4;
      const int bm = bmBase + m0 + mj;
      float zv = stage[mj][592];
#pragma unroll
      for (int c = 0; c < 16; c++) zv = fmaf(stage[mj][576 + c], sh2[mj][c], zv);
      float hm = __fdividef(1.0f, 1.0f + __expf(-zv));
      hm = fminf(fmaxf(hm, 1e-4f), 1.0f - 1e-4f);
      const float om = 1.0f - hm;
      ws[POS_OFF + bm] = __logf(hm) * om * om * mask[bm];
    }
    __syncthreads();  // stage reused next round
  }

  // ======== Phase B: negative loss; direct sch_feat read + wave-private transpose ====
  const float* tg0 = target + (size_t)bmBase * HWc;
  uint* xpw = xp[wid];
  const int rdOff = (g < 2) ? (g * 4) : 8;   // dword offset in 12-dword pixel row
  const int wslot = nb * 4 + wid;            // 0..255 per (b,mg)
  const int itS = (wslot * ITERS) >> 8;
  const int itE = ((wslot + 1) * ITERS) >> 8;

  float acc = 0.0f;
  for (int it = itS; it < itE; ++it) {
    const int base = it * 64, px = base + lane;
    const float* s = sf + px;
    float cv[16];
#pragma unroll
    for (int c = 0; c < 16; c++) cv[c] = s[(size_t)c * HWc];
    uint pk[8];
#pragma unroll
    for (int q = 0; q < 8; q++) pk[q] = pkbf(cv[2 * q], cv[2 * q + 1]);
    const int hh = px / Wc, xx = px - hh * Wc;
    const uint qc = pkbf((float)xx * 0.0078125f, (float)hh * 0.0078125f);
    uint* row = xpw + lane * 12;
    // same-type (uint4) accesses on both sides; fence stops compiler reordering.
    *(uint4*)(row + 0) = make_uint4(pk[0], pk[1], pk[2], pk[3]);
    *(uint4*)(row + 4) = make_uint4(pk[4], pk[5], pk[6], pk[7]);
    *(uint4*)(row + 8) = make_uint4(qc, 0u, 0u, 0u);
    asm volatile("s_waitcnt lgkmcnt(0)" ::: "memory");
    __builtin_amdgcn_sched_barrier(0);
    uint4 ld[4];
#pragma unroll
    for (int c = 0; c < 4; c++) ld[c] = *(const uint4*)(xpw + (16 * c + o) * 12 + rdOff);

#pragma unroll 1
    for (int j = 0; j < MPB; ++j) {
      FR A1, A2;
      {
        uint4 u1 = sA1[j][lane];
        A1.u[0] = u1.x; A1.u[1] = u1.y; A1.u[2] = u1.z; A1.u[3] = u1.w;
        uint2 u2 = sA2[j][lane];
        A2.u[0] = u2.x; A2.u[1] = u2.y; A2.u[2] = 0u; A2.u[3] = 0u;
      }
      const f32x4 cw3 = *(const f32x4*)&sW3[j][g * 4];
      const float b3v = sW3[j][16];
      const f32x4 cc1 = *(const f32x4*)&sCB[j][g * 4];
      const f32x4 cc2 = *(const f32x4*)&sCB[j][16 + g * 4];
      const float tval = tg0[(size_t)j * HWc + base + lane];

      float Z[4];
#pragma unroll
      for (int c = 0; c < 4; c++) {
        FR B1;
        B1.u[0] = ld[c].x; B1.u[1] = ld[c].y; B1.u[2] = ld[c].z; B1.u[3] = ld[c].w;
        f32x4 d1 = __builtin_amdgcn_mfma_f32_16x16x32_bf16(A1.v, B1.v, cc1, 0, 0, 0);
        FR B2;
        B2.u[0] = pkbf(fmaxf(d1[0], 0.0f), fmaxf(d1[1], 0.0f));
        B2.u[1] = pkbf(fmaxf(d1[2], 0.0f), fmaxf(d1[3], 0.0f));
        B2.u[2] = 0u; B2.u[3] = 0u;
        f32x4 d2 = __builtin_amdgcn_mfma_f32_16x16x32_bf16(A2.v, B2.v, cc2, 0, 0, 0);
        float zp = fmaxf(d2[0], 0.0f) * cw3[0] + fmaxf(d2[1], 0.0f) * cw3[1] +
                   fmaxf(d2[2], 0.0f) * cw3[2] + fmaxf(d2[3], 0.0f) * cw3[3];
        Z[c] = xsum32(xsum16(zp));
      }
      float zz = (lane & 32) ? ((lane & 16) ? Z[3] : Z[2]) : ((lane & 16) ? Z[1] : Z[0]);
      zz += b3v;
      float hm = __fdividef(1.0f, 1.0f + __expf(-zz));
      hm = fminf(fmaxf(hm, 1e-4f), 1.0f - 1e-4f);
      const float u = 1.0f - tval;
      const float u2 = u * u;
      acc += __logf(1.0f - hm) * hm * hm * (u2 * u2);
    }
  }

  red[tid] = acc;
  __syncthreads();
  for (int s2 = 128; s2 > 0; s2 >>= 1) {
    if (tid < s2) red[tid] += red[tid + s2];
    __syncthreads();
  }
  if (tid == 0) ws[blockIdx.x] = red[0];
}

// ---- final reduction ----
__global__ __launch_bounds__(256) void sch_final(const float* __restrict__ ws,
                                                 const float* __restrict__ mask,
                                                 float* __restrict__ out) {
  __shared__ float red[256];
  const int t = threadIdx.x;

  float s = 0.0f;
  for (int i = t; i < NEG_BLOCKS; i += 256) s += ws[i];
  red[t] = s; __syncthreads();
  for (int k = 128; k > 0; k >>= 1) { if (t < k) red[t] += red[t + k]; __syncthreads(); }
  const float neg = red[0];
  __syncthreads();

  float pv = (t < Bc * Mc) ? ws[POS_OFF + t] : 0.0f;
  red[t] = pv; __syncthreads();
  for (int k = 128; k > 0; k >>= 1) { if (t < k) red[t] += red[t + k]; __syncthreads(); }
  const float pos = red[0];
  __syncthreads();

  float mv = (t < Bc * Mc) ? mask[t] : 0.0f;
  red[t] = mv; __syncthreads();
  for (int k = 128; k > 0; k >>= 1) { if (t < k) red[t] += red[t + k]; __syncthreads(); }

  if (t == 0) {
    float np = red[0];
    out[0] = (np == 0.0f) ? (-neg) : (-(pos + neg) / fmaxf(np, 1.0f));
  }
}

extern "C" void kernel_launch(void* const* d_in, const int* in_sizes, int n_in,
                              void* d_out, int out_size, void* d_ws, size_t ws_size,
                              hipStream_t stream) {
  const float* sch_feat    = (const float*)d_in[0];
  const float* conv_weight = (const float*)d_in[1];
  const float* mask        = (const float*)d_in[2];
  const int*   pre_ind     = (const int*)d_in[3];
  const float* target      = (const float*)d_in[4];
  const int*   ind         = (const int*)d_in[5];
  float* out = (float*)d_out;
  float* ws  = (float*)d_ws;

  sch_fused<<<dim3(NEG_BLOCKS), dim3(256), 0, stream>>>(
      sch_feat, conv_weight, pre_ind, ind, mask, target, ws);
  sch_final<<<dim3(1), dim3(256), 0, stream>>>(ws, mask, out);
}

// Round 12
// 49.040 us; speedup vs baseline: 1.2426x; 1.2426x over previous
//
#include <hip/hip_runtime.h>

typedef unsigned int uint;
typedef unsigned short ushort;

constexpr int Bc = 4, Mc = 32, Hc = 152, Wc = 272;
constexpr int HWc = Hc * Wc;              // 41344
constexpr int WTc = 593;                  // (16+2)*16 + 16 + 16*16 + 16 + 16 + 1
constexpr int MG = 4;                     // m-groups per batch
constexpr int MPB = 8;                    // m's per block (MG*MPB = 32)
constexpr int NBCH = 64;                  // pixel-chunk blocks per (b,mg)
constexpr int NEG_BLOCKS = Bc * MG * NBCH;// 1024
constexpr int ITERS = HWc / 64;           // 646
constexpr int POS_OFF = 1024;             // ws float idx of pos terms
constexpr int APK1_OFF = 2048;                      // [128][64] uint4
constexpr int APK2_OFF = APK1_OFF + 128 * 64 * 4;   // 34816
constexpr int W3B3_OFF = APK2_OFF + 128 * 64 * 4;   // 67584  [128][20] fp32 w3+b3
constexpr int CB_OFF   = W3B3_OFF + 128 * 20;       // 70144  [128][32] fp32 c1eff+b2
constexpr size_t XOFF_BYTES = (size_t)(CB_OFF + 128 * 32) * 4;  // 296960 (64B aligned)
constexpr int GRPB = HWc / 16;            // 2584 pixel-groups per batch
constexpr int GSTRIDE = 576;              // bytes per 16-px group (256+256+64)
constexpr int XCVT_BLOCKS = 162 * Bc;     // 648

using f32x4 = __attribute__((ext_vector_type(4))) float;
using bf16x8 = __attribute__((ext_vector_type(8))) short;

__device__ inline uint pkbf(float lo, float hi) {
  uint r;
  asm("v_cvt_pk_bf16_f32 %0, %1, %2" : "=v"(r) : "v"(lo), "v"(hi));
  return r;
}

// convention-immune cross-half sums: pr[0]+pr[1] == x[l] + x[l^K] for self-swap
__device__ inline float xsum16(float x) {
#if __has_builtin(__builtin_amdgcn_permlane16_swap)
  uint u = __float_as_uint(x);
  auto pr = __builtin_amdgcn_permlane16_swap(u, u, false, false);
  return __uint_as_float(pr[0]) + __uint_as_float(pr[1]);
#else
  return x + __shfl_xor(x, 16);
#endif
}
__device__ inline float xsum32(float x) {
#if __has_builtin(__builtin_amdgcn_permlane32_swap)
  uint u = __float_as_uint(x);
  auto pr = __builtin_amdgcn_permlane32_swap(u, u, false, false);
  return __uint_as_float(pr[0]) + __uint_as_float(pr[1]);
#else
  return x + __shfl_xor(x, 32);
#endif
}

union FR { uint u[4]; bf16x8 v; };
__device__ inline FR toFR(uint4 q) { FR f; f.u[0]=q.x; f.u[1]=q.y; f.u[2]=q.z; f.u[3]=q.w; return f; }

// ---- fused pre-pass: xcvt blocks + prep/pos blocks ----
__global__ __launch_bounds__(256) void fused_pre(const float* __restrict__ sf_all,
                                                 const float* __restrict__ cw,
                                                 const int* __restrict__ pre_ind,
                                                 const int* __restrict__ ind,
                                                 const float* __restrict__ mask,
                                                 unsigned char* __restrict__ xb,
                                                 float* __restrict__ ws) {
  __shared__ float sw[WTc];
  __shared__ float sh1[16], sh2[16];
  const int blk = blockIdx.x, tid = threadIdx.x;

  if (blk < XCVT_BLOCKS) {
    // sch_feat fp32 [b][c][hw] -> bf16 tile-interleaved groups of 16 px:
    // [256B ch0-7][256B ch8-15][64B coords(x/128,y/128)]
    const int b = blk / 162, bx = blk - b * 162;
    const int px = bx * 256 + tid;
    if (px < HWc) {
      const float* s = sf_all + (size_t)b * 16 * HWc + px;
      uint q[8];
#pragma unroll
      for (int i = 0; i < 8; i++) q[i] = pkbf(s[(size_t)(2 * i) * HWc], s[(size_t)(2 * i + 1) * HWc]);
      const int hh = px / Wc, xx = px - hh * Wc;
      const uint q8 = pkbf((float)xx * 0.0078125f, (float)hh * 0.0078125f);
      const int grp = px >> 4, o = px & 15;
      unsigned char* gb = xb + ((size_t)b * GRPB + grp) * GSTRIDE;
      *(uint4*)(gb + o * 16) = make_uint4(q[0], q[1], q[2], q[3]);
      *(uint4*)(gb + 256 + o * 16) = make_uint4(q[4], q[5], q[6], q[7]);
      *(uint*)(gb + 512 + o * 4) = q8;
    }
    return;
  }

  // prep: gather 593 weights once per (b,m); pack A-frags + fp32 C-vectors; pos term
  const int bm = blk - XCVT_BLOCKS, b = bm >> 5;
  const int p = pre_ind[bm];
  const float* wcol = cw + (size_t)b * WTc * HWc + p;
  for (int j = tid; j < WTc; j += 256) sw[j] = wcol[(size_t)j * HWc];
  __syncthreads();

  const float x0 = (float)(p % Wc);
  const float y0 = (float)p / (float)Wc;  // float division of flat index (per reference)

  if (tid < 64) {
    const int g = tid >> 4, o = tid & 15;
    float a1f[8], a2f[8];
#pragma unroll
    for (int e = 0; e < 8; e++) {
      int k = 8 * g + e;
      a1f[e] = (k < 18) ? sw[o * 18 + k] : 0.0f;  // k=16,17 -> coord weights
      // A2 matched to D1's native distribution: group g carries channels 4g..4g+3
      a2f[e] = (e < 4) ? sw[304 + o * 16 + 4 * g + e] : 0.0f;
    }
    uint4 u1, u2;
    u1.x = pkbf(a1f[0], a1f[1]); u1.y = pkbf(a1f[2], a1f[3]);
    u1.z = pkbf(a1f[4], a1f[5]); u1.w = pkbf(a1f[6], a1f[7]);
    u2.x = pkbf(a2f[0], a2f[1]); u2.y = pkbf(a2f[2], a2f[3]);
    u2.z = 0u; u2.w = 0u;
    ((uint4*)(ws + APK1_OFF))[bm * 64 + tid] = u1;
    ((uint4*)(ws + APK2_OFF))[bm * 64 + tid] = u2;
  } else if (tid >= 80 && tid < 97) {
    const int k = tid - 80;  // w3[0..15], b3 at 16
    ws[W3B3_OFF + bm * 20 + k] = (k < 16) ? sw[576 + k] : sw[592];
  } else if (tid >= 100 && tid < 116) {
    const int row = tid - 100;  // fp32 c1eff (coords folded) + b2
    ws[CB_OFF + bm * 32 + row] =
        sw[288 + row] - (sw[row * 18 + 16] * x0 + sw[row * 18 + 17] * y0) * 0.0078125f;
    ws[CB_OFF + bm * 32 + 16 + row] = sw[560 + row];
  }

  // positive-sample term, exact fp32, layer-parallel (16 threads)
  if (tid >= 64 && tid < 80) {
    const int oo = tid - 64;
    const float* sf = sf_all + (size_t)b * 16 * HWc;
    const int pi = ind[bm];
    float f[18];
#pragma unroll
    for (int c = 0; c < 16; c++) f[c] = sf[(size_t)c * HWc + pi];
    const int hh = pi / Wc;
    f[16] = ((float)(pi - hh * Wc) - x0) * 0.0078125f;
    f[17] = ((float)hh - y0) * 0.0078125f;
    float a = sw[288 + oo];
#pragma unroll
    for (int c = 0; c < 18; c++) a = fmaf(sw[oo * 18 + c], f[c], a);
    sh1[oo] = fmaxf(a, 0.0f);
  }
  __syncthreads();
  if (tid >= 64 && tid < 80) {
    const int oo = tid - 64;
    float a = sw[560 + oo];
#pragma unroll
    for (int c = 0; c < 16; c++) a = fmaf(sw[304 + oo * 16 + c], sh1[c], a);
    sh2[oo] = fmaxf(a, 0.0f);
  }
  __syncthreads();
  if (tid == 64) {
    float zv = sw[592];
#pragma unroll
    for (int c = 0; c < 16; c++) zv = fmaf(sw[576 + c], sh2[c], zv);
    float hm = __fdividef(1.0f, 1.0f + __expf(-zv));
    hm = fminf(fmaxf(hm, 1e-4f), 1.0f - 1e-4f);
    const float om = 1.0f - hm;
    ws[POS_OFF + bm] = __logf(hm) * om * om * mask[bm];
  }
}

// ---- main negative-loss kernel: each block does 8 m's per pixel chunk ----
__global__ __launch_bounds__(256, 4) void sch_neg(const float* __restrict__ target,
                                                  const unsigned char* __restrict__ xbf,
                                                  float* __restrict__ ws) {
  __shared__ uint4 sA1[MPB][64];
  __shared__ uint2 sA2[MPB][64];
  __shared__ float sW3[MPB][20];   // w3[16], b3, pad
  __shared__ float sCB[MPB][32];   // c1eff[16], b2[16]
  __shared__ float red[256];

  const int tid = threadIdx.x;
  const int lane = tid & 63;
  const int wid = tid >> 6;
  // XCD-aware: batch b pinned to XCD pair {2b,2b+1}
  const int xcd = blockIdx.x & 7;
  const int slot = blockIdx.x >> 3;        // 0..127
  const int b = xcd >> 1;
  const int mg = slot & 3;
  const int nb = ((slot >> 2) << 1) | (xcd & 1);  // 0..63
  const int bmBase = b * 32 + mg * MPB;

  // ---- stage per-m constants into LDS ----
  for (int e = tid; e < MPB * 64; e += 256) {
    const int j = e >> 6, l = e & 63;
    sA1[j][l] = ((const uint4*)(ws + APK1_OFF))[(bmBase + j) * 64 + l];
    uint4 a2 = ((const uint4*)(ws + APK2_OFF))[(bmBase + j) * 64 + l];
    sA2[j][l] = make_uint2(a2.x, a2.y);
  }
  for (int e = tid; e < MPB * 20; e += 256)
    sW3[e / 20][e % 20] = ws[W3B3_OFF + (bmBase + e / 20) * 20 + (e % 20)];
  for (int e = tid; e < MPB * 32; e += 256)
    sCB[e >> 5][e & 31] = ws[CB_OFF + (bmBase + (e >> 5)) * 32 + (e & 31)];
  __syncthreads();

  const int g = lane >> 4, o = lane & 15;
  const unsigned char* xb = xbf + (size_t)b * GRPB * GSTRIDE;
  const float* tg0 = target + (size_t)bmBase * HWc;
  const int addrOff = (g < 2) ? ((g << 8) + (o << 4)) : (512 + (o << 2));
  const int wslot = nb * 4 + wid;                   // 0..255 per (b,mg)
  const int itS = (wslot * ITERS) >> 8;
  const int itE = ((wslot + 1) * ITERS) >> 8;

  float acc = 0.0f;
  for (int it = itS; it < itE; ++it) {
    const unsigned char* gb = xb + (size_t)it * (4 * GSTRIDE);
    uint4 ld[4];
#pragma unroll
    for (int c = 0; c < 4; c++) ld[c] = *(const uint4*)(gb + c * GSTRIDE + addrOff);
    const int off64 = it * 64 + lane;

    // 1-deep software pipeline over the 8 m's
    FR cA1 = toFR(sA1[0][lane]);
    FR cA2; { uint2 u2 = sA2[0][lane]; cA2.u[0] = u2.x; cA2.u[1] = u2.y; cA2.u[2] = 0u; cA2.u[3] = 0u; }
    f32x4 cw3 = *(const f32x4*)&sW3[0][g * 4];
    float cb3 = sW3[0][16];
    f32x4 cc1 = *(const f32x4*)&sCB[0][g * 4];
    f32x4 cc2 = *(const f32x4*)&sCB[0][16 + g * 4];
    const float* tj = tg0;
    float ctv = tj[off64];

    for (int j = 0; j < MPB; ++j) {
      FR nA1, nA2; f32x4 nw3, nc1, nc2; float nb3 = 0.f, ntv = 0.f;
      if (j < MPB - 1) {
        nA1 = toFR(sA1[j + 1][lane]);
        { uint2 u2 = sA2[j + 1][lane]; nA2.u[0] = u2.x; nA2.u[1] = u2.y; nA2.u[2] = 0u; nA2.u[3] = 0u; }
        nw3 = *(const f32x4*)&sW3[j + 1][g * 4];
        nb3 = sW3[j + 1][16];
        nc1 = *(const f32x4*)&sCB[j + 1][g * 4];
        nc2 = *(const f32x4*)&sCB[j + 1][16 + g * 4];
        ntv = (tj + HWc)[off64];
      }

      float Z[4];
#pragma unroll
      for (int c = 0; c < 4; c++) {
        FR B1;
        B1.u[0] = ld[c].x; B1.u[1] = ld[c].y; B1.u[2] = ld[c].z; B1.u[3] = ld[c].w;
        f32x4 d1 = __builtin_amdgcn_mfma_f32_16x16x32_bf16(cA1.v, B1.v, cc1, 0, 0, 0);
        FR B2;
        B2.u[0] = pkbf(fmaxf(d1[0], 0.0f), fmaxf(d1[1], 0.0f));
        B2.u[1] = pkbf(fmaxf(d1[2], 0.0f), fmaxf(d1[3], 0.0f));
        B2.u[2] = 0u; B2.u[3] = 0u;
        f32x4 d2 = __builtin_amdgcn_mfma_f32_16x16x32_bf16(cA2.v, B2.v, cc2, 0, 0, 0);
        float zp = fmaxf(d2[0], 0.0f) * cw3[0] + fmaxf(d2[1], 0.0f) * cw3[1] +
                   fmaxf(d2[2], 0.0f) * cw3[2] + fmaxf(d2[3], 0.0f) * cw3[3];
        Z[c] = xsum32(xsum16(zp));
      }
      float zz = (lane & 32) ? ((lane & 16) ? Z[3] : Z[2]) : ((lane & 16) ? Z[1] : Z[0]);
      zz += cb3;
      float hm = __fdividef(1.0f, 1.0f + __expf(-zz));
      hm = fminf(fmaxf(hm, 1e-4f), 1.0f - 1e-4f);
      const float u = 1.0f - ctv;
      const float u2 = u * u;
      acc += __logf(1.0f - hm) * hm * hm * (u2 * u2);

      if (j < MPB - 1) {
        cA1 = nA1; cA2 = nA2; cw3 = nw3; cb3 = nb3; cc1 = nc1; cc2 = nc2; ctv = ntv;
        tj += HWc;
      }
    }
  }

  red[tid] = acc;
  __syncthreads();
  for (int s = 128; s > 0; s >>= 1) {
    if (tid < s) red[tid] += red[tid + s];
    __syncthreads();
  }
  if (tid == 0) ws[blockIdx.x] = red[0];
}

// ---- final reduction ----
__global__ __launch_bounds__(256) void sch_final(const float* __restrict__ ws,
                                                 const float* __restrict__ mask,
                                                 float* __restrict__ out) {
  __shared__ float red[256];
  const int t = threadIdx.x;

  float s = 0.0f;
  for (int i = t; i < NEG_BLOCKS; i += 256) s += ws[i];
  red[t] = s; __syncthreads();
  for (int k = 128; k > 0; k >>= 1) { if (t < k) red[t] += red[t + k]; __syncthreads(); }
  const float neg = red[0];
  __syncthreads();

  float pv = (t < Bc * Mc) ? ws[POS_OFF + t] : 0.0f;
  red[t] = pv; __syncthreads();
  for (int k = 128; k > 0; k >>= 1) { if (t < k) red[t] += red[t + k]; __syncthreads(); }
  const float pos = red[0];
  __syncthreads();

  float mv = (t < Bc * Mc) ? mask[t] : 0.0f;
  red[t] = mv; __syncthreads();
  for (int k = 128; k > 0; k >>= 1) { if (t < k) red[t] += red[t + k]; __syncthreads(); }

  if (t == 0) {
    float np = red[0];
    out[0] = (np == 0.0f) ? (-neg) : (-(pos + neg) / fmaxf(np, 1.0f));
  }
}

extern "C" void kernel_launch(void* const* d_in, const int* in_sizes, int n_in,
                              void* d_out, int out_size, void* d_ws, size_t ws_size,
                              hipStream_t stream) {
  const float* sch_feat    = (const float*)d_in[0];
  const float* conv_weight = (const float*)d_in[1];
  const float* mask        = (const float*)d_in[2];
  const int*   pre_ind     = (const int*)d_in[3];
  const float* target      = (const float*)d_in[4];
  const int*   ind         = (const int*)d_in[5];
  float* out = (float*)d_out;
  float* ws  = (float*)d_ws;
  unsigned char* xbf = (unsigned char*)d_ws + XOFF_BYTES;

  fused_pre<<<dim3(XCVT_BLOCKS + Bc * Mc), dim3(256), 0, stream>>>(
      sch_feat, conv_weight, pre_ind, ind, mask, xbf, ws);
  sch_neg<<<dim3(NEG_BLOCKS), dim3(256), 0, stream>>>(target, xbf, ws);
  sch_final<<<dim3(1), dim3(256), 0, stream>>>(ws, mask, out);
}